// Round 1
// baseline (2779.881 us; speedup 1.0000x reference)
//
#include <hip/hip_runtime.h>

#define ALPHA 0.5f

// ---------------- GEMM: support = input @ W  (fp32, tiled 64x64, 4x4/thread) ----------------
#define BM 64
#define BN 64
#define BK 16

__global__ __launch_bounds__(256) void gemm_tiled(
    const float* __restrict__ A,   // [M,256]
    const float* __restrict__ W,   // [256,256]
    float* __restrict__ C,         // [M,256]
    int M) {
  __shared__ float As[BK][BM];   // A tile, transposed: As[k][row]
  __shared__ float Bs[BK][BN];   // B tile: Bs[k][col]

  const int tid = threadIdx.x;
  const int tx = tid & 15;        // col group 0..15
  const int ty = tid >> 4;        // row group 0..15
  const int blockRow = blockIdx.x * BM;
  const int blockCol = blockIdx.y * BN;

  // A-load mapping: each thread loads one float4 along K
  const int a_row = tid >> 2;          // 0..63
  const int a_k4  = (tid & 3) * 4;     // 0,4,8,12
  // B-load mapping: each thread loads one float4 along N
  const int b_row = tid >> 4;          // 0..15
  const int b_c4  = (tid & 15) * 4;    // 0..60

  float acc[4][4] = {};

  for (int k0 = 0; k0 < 256; k0 += BK) {
    // load A tile (guard M edge)
    {
      int gr = blockRow + a_row;
      float4 v = make_float4(0.f, 0.f, 0.f, 0.f);
      if (gr < M) v = *reinterpret_cast<const float4*>(&A[gr * 256 + k0 + a_k4]);
      As[a_k4 + 0][a_row] = v.x;
      As[a_k4 + 1][a_row] = v.y;
      As[a_k4 + 2][a_row] = v.z;
      As[a_k4 + 3][a_row] = v.w;
    }
    // load B tile
    {
      float4 v = *reinterpret_cast<const float4*>(&W[(k0 + b_row) * 256 + blockCol + b_c4]);
      *reinterpret_cast<float4*>(&Bs[b_row][b_c4]) = v;
    }
    __syncthreads();
    #pragma unroll
    for (int k = 0; k < BK; ++k) {
      float4 ra = *reinterpret_cast<const float4*>(&As[k][ty * 4]);
      float4 rb = *reinterpret_cast<const float4*>(&Bs[k][tx * 4]);
      float a_[4] = {ra.x, ra.y, ra.z, ra.w};
      float b_[4] = {rb.x, rb.y, rb.z, rb.w};
      #pragma unroll
      for (int i = 0; i < 4; ++i)
        #pragma unroll
        for (int j = 0; j < 4; ++j)
          acc[i][j] += a_[i] * b_[j];
    }
    __syncthreads();
  }

  #pragma unroll
  for (int i = 0; i < 4; ++i) {
    int gr = blockRow + ty * 4 + i;
    if (gr < M) {
      float4 v = make_float4(acc[i][0], acc[i][1], acc[i][2], acc[i][3]);
      *reinterpret_cast<float4*>(&C[gr * 256 + blockCol + tx * 4]) = v;
    }
  }
}

// ---------------- out = (1-alpha) * init ----------------
__global__ void init_out(const float* __restrict__ init, float* __restrict__ out, int n4) {
  int i = blockIdx.x * blockDim.x + threadIdx.x;
  int stride = gridDim.x * blockDim.x;
  for (; i < n4; i += stride) {
    float4 v = reinterpret_cast<const float4*>(init)[i];
    v.x *= (1.f - ALPHA);
    v.y *= (1.f - ALPHA);
    v.z *= (1.f - ALPHA);
    v.w *= (1.f - ALPHA);
    reinterpret_cast<float4*>(out)[i] = v;
  }
}

// ---------------- scatter: out[dst] += alpha * w * support[src] ----------------
// One wave (64 lanes) per edge; each lane handles 4 contiguous features (float4).
__global__ __launch_bounds__(256) void scatter_edges(
    const float* __restrict__ support,
    const int* __restrict__ src,
    const int* __restrict__ dst,
    const float* __restrict__ w,
    float* __restrict__ out, int E) {
  int edge = blockIdx.x * (blockDim.x >> 6) + (threadIdx.x >> 6);
  if (edge >= E) return;
  int lane = threadIdx.x & 63;
  int s = src[edge];
  int d = dst[edge];
  float wt = w[edge] * ALPHA;
  float4 v = *reinterpret_cast<const float4*>(&support[s * 256 + lane * 4]);
  float* o = &out[d * 256 + lane * 4];
  atomicAdd(o + 0, wt * v.x);
  atomicAdd(o + 1, wt * v.y);
  atomicAdd(o + 2, wt * v.z);
  atomicAdd(o + 3, wt * v.w);
}

// ---------------- relu in place ----------------
__global__ void relu_kernel(float* __restrict__ out, int n4) {
  int i = blockIdx.x * blockDim.x + threadIdx.x;
  int stride = gridDim.x * blockDim.x;
  for (; i < n4; i += stride) {
    float4 v = reinterpret_cast<float4*>(out)[i];
    v.x = fmaxf(v.x, 0.f);
    v.y = fmaxf(v.y, 0.f);
    v.z = fmaxf(v.z, 0.f);
    v.w = fmaxf(v.w, 0.f);
    reinterpret_cast<float4*>(out)[i] = v;
  }
}

extern "C" void kernel_launch(void* const* d_in, const int* in_sizes, int n_in,
                              void* d_out, int out_size, void* d_ws, size_t ws_size,
                              hipStream_t stream) {
  const float* input   = (const float*)d_in[0];  // [N,256]
  const int*   adj_src = (const int*)d_in[1];    // [E]
  const int*   adj_dst = (const int*)d_in[2];    // [E]
  const float* adj_w   = (const float*)d_in[3];  // [E]
  const float* init_in = (const float*)d_in[4];  // [N,256]
  const float* weight  = (const float*)d_in[5];  // [256,256]
  float* out = (float*)d_out;

  const int N = in_sizes[0] / 256;  // 50000
  const int E = in_sizes[1];        // 800000

  float* support = (float*)d_ws;    // [N,256] fp32 = 51.2 MB

  // 1) support = input @ W
  dim3 gg((N + BM - 1) / BM, 256 / BN);
  gemm_tiled<<<gg, 256, 0, stream>>>(input, weight, support, N);

  // 2) out = (1-alpha) * init
  int n4 = N * 256 / 4;
  init_out<<<2048, 256, 0, stream>>>(init_in, out, n4);

  // 3) out[dst] += alpha * w * support[src]
  scatter_edges<<<(E + 3) / 4, 256, 0, stream>>>(support, adj_src, adj_dst, adj_w, out, E);

  // 4) relu
  relu_kernel<<<2048, 256, 0, stream>>>(out, n4);
}

// Round 2
// 403.431 us; speedup vs baseline: 6.8906x; 6.8906x over previous
//
#include <hip/hip_runtime.h>

#define ALPHA 0.5f

// ---------------- GEMM: support = input @ W  (fp32, tiled 64x64, 4x4/thread) ----------------
#define BM 64
#define BN 64
#define BK 16

__global__ __launch_bounds__(256) void gemm_tiled(
    const float* __restrict__ A,   // [M,256]
    const float* __restrict__ W,   // [256,256]
    float* __restrict__ C,         // [M,256]
    int M) {
  __shared__ float As[BK][BM];
  __shared__ float Bs[BK][BN];

  const int tid = threadIdx.x;
  const int tx = tid & 15;
  const int ty = tid >> 4;
  const int blockRow = blockIdx.x * BM;
  const int blockCol = blockIdx.y * BN;

  const int a_row = tid >> 2;
  const int a_k4  = (tid & 3) * 4;
  const int b_row = tid >> 4;
  const int b_c4  = (tid & 15) * 4;

  float acc[4][4] = {};

  for (int k0 = 0; k0 < 256; k0 += BK) {
    {
      int gr = blockRow + a_row;
      float4 v = make_float4(0.f, 0.f, 0.f, 0.f);
      if (gr < M) v = *reinterpret_cast<const float4*>(&A[gr * 256 + k0 + a_k4]);
      As[a_k4 + 0][a_row] = v.x;
      As[a_k4 + 1][a_row] = v.y;
      As[a_k4 + 2][a_row] = v.z;
      As[a_k4 + 3][a_row] = v.w;
    }
    {
      float4 v = *reinterpret_cast<const float4*>(&W[(k0 + b_row) * 256 + blockCol + b_c4]);
      *reinterpret_cast<float4*>(&Bs[b_row][b_c4]) = v;
    }
    __syncthreads();
    #pragma unroll
    for (int k = 0; k < BK; ++k) {
      float4 ra = *reinterpret_cast<const float4*>(&As[k][ty * 4]);
      float4 rb = *reinterpret_cast<const float4*>(&Bs[k][tx * 4]);
      float a_[4] = {ra.x, ra.y, ra.z, ra.w};
      float b_[4] = {rb.x, rb.y, rb.z, rb.w};
      #pragma unroll
      for (int i = 0; i < 4; ++i)
        #pragma unroll
        for (int j = 0; j < 4; ++j)
          acc[i][j] += a_[i] * b_[j];
    }
    __syncthreads();
  }

  #pragma unroll
  for (int i = 0; i < 4; ++i) {
    int gr = blockRow + ty * 4 + i;
    if (gr < M) {
      float4 v = make_float4(acc[i][0], acc[i][1], acc[i][2], acc[i][3]);
      *reinterpret_cast<float4*>(&C[gr * 256 + blockCol + tx * 4]) = v;
    }
  }
}

// ---------------- CSR build step 1: degree histogram ----------------
__global__ void histogram_dst(const int* __restrict__ dst, int* __restrict__ deg, int E) {
  int i = blockIdx.x * blockDim.x + threadIdx.x;
  if (i < E) atomicAdd(&deg[dst[i]], 1);
}

// ---------------- CSR build step 2: exclusive scan (single block, chunked) ----------------
__global__ __launch_bounds__(1024) void scan_deg(const int* __restrict__ deg,
                                                 int* __restrict__ row_ptr,
                                                 int* __restrict__ cursor, int N) {
  __shared__ int sh[1024];
  __shared__ int carry;
  if (threadIdx.x == 0) carry = 0;
  __syncthreads();
  for (int base = 0; base < N; base += 1024) {
    int i = base + threadIdx.x;
    int v = (i < N) ? deg[i] : 0;
    sh[threadIdx.x] = v;
    __syncthreads();
    #pragma unroll
    for (int off = 1; off < 1024; off <<= 1) {
      int t = (threadIdx.x >= off) ? sh[threadIdx.x - off] : 0;
      __syncthreads();
      sh[threadIdx.x] += t;
      __syncthreads();
    }
    int excl = carry + sh[threadIdx.x] - v;
    if (i < N) {
      row_ptr[i] = excl;
      cursor[i]  = excl;
    }
    __syncthreads();
    if (threadIdx.x == 1023) carry += sh[1023];
    __syncthreads();
  }
}

// ---------------- CSR build step 3: reindex edges ----------------
__global__ void reindex_edges(const int* __restrict__ src, const int* __restrict__ dst,
                              const float* __restrict__ w, int* __restrict__ cursor,
                              int* __restrict__ cols, float* __restrict__ vals, int E) {
  int i = blockIdx.x * blockDim.x + threadIdx.x;
  if (i < E) {
    int d = dst[i];
    int slot = atomicAdd(&cursor[d], 1);
    cols[slot] = src[i];
    vals[slot] = w[i];
  }
}

// ---------------- aggregate (pull): one wave per dst node, fused blend+relu ----------------
__global__ __launch_bounds__(256) void aggregate(
    const float* __restrict__ support,
    const int* __restrict__ row_ptr,
    const int* __restrict__ deg,
    const int* __restrict__ cols,
    const float* __restrict__ vals,
    const float* __restrict__ init,
    float* __restrict__ out, int N) {
  int node = blockIdx.x * 4 + (threadIdx.x >> 6);
  if (node >= N) return;
  int lane = threadIdx.x & 63;
  int start = row_ptr[node];
  int cnt = deg[node];

  float4 acc = make_float4(0.f, 0.f, 0.f, 0.f);
  for (int e = 0; e < cnt; ++e) {
    int s = cols[start + e];
    float wt = vals[start + e];
    float4 v = *reinterpret_cast<const float4*>(&support[s * 256 + lane * 4]);
    acc.x += wt * v.x;
    acc.y += wt * v.y;
    acc.z += wt * v.z;
    acc.w += wt * v.w;
  }
  float4 ini = *reinterpret_cast<const float4*>(&init[node * 256 + lane * 4]);
  float4 o;
  o.x = fmaxf(ALPHA * acc.x + (1.f - ALPHA) * ini.x, 0.f);
  o.y = fmaxf(ALPHA * acc.y + (1.f - ALPHA) * ini.y, 0.f);
  o.z = fmaxf(ALPHA * acc.z + (1.f - ALPHA) * ini.z, 0.f);
  o.w = fmaxf(ALPHA * acc.w + (1.f - ALPHA) * ini.w, 0.f);
  *reinterpret_cast<float4*>(&out[node * 256 + lane * 4]) = o;
}

extern "C" void kernel_launch(void* const* d_in, const int* in_sizes, int n_in,
                              void* d_out, int out_size, void* d_ws, size_t ws_size,
                              hipStream_t stream) {
  const float* input   = (const float*)d_in[0];  // [N,256]
  const int*   adj_src = (const int*)d_in[1];    // [E]
  const int*   adj_dst = (const int*)d_in[2];    // [E]
  const float* adj_w   = (const float*)d_in[3];  // [E]
  const float* init_in = (const float*)d_in[4];  // [N,256]
  const float* weight  = (const float*)d_in[5];  // [256,256]
  float* out = (float*)d_out;

  const int N = in_sizes[0] / 256;  // 50000
  const int E = in_sizes[1];        // 800000

  // workspace layout
  char* ws = (char*)d_ws;
  float* support = (float*)ws;                       ws += (size_t)N * 256 * 4;  // 51.2 MB
  int*   deg     = (int*)ws;                         ws += (size_t)N * 4;
  int*   row_ptr = (int*)ws;                         ws += (size_t)N * 4;
  int*   cursor  = (int*)ws;                         ws += (size_t)N * 4;
  int*   cols    = (int*)ws;                         ws += (size_t)E * 4;
  float* vals    = (float*)ws;                       ws += (size_t)E * 4;

  // 1) support = input @ W
  dim3 gg((N + BM - 1) / BM, 256 / BN);
  gemm_tiled<<<gg, 256, 0, stream>>>(input, weight, support, N);

  // 2) CSR build
  hipMemsetAsync(deg, 0, (size_t)N * 4, stream);
  histogram_dst<<<(E + 255) / 256, 256, 0, stream>>>(adj_dst, deg, E);
  scan_deg<<<1, 1024, 0, stream>>>(deg, row_ptr, cursor, N);
  reindex_edges<<<(E + 255) / 256, 256, 0, stream>>>(adj_src, adj_dst, adj_w, cursor, cols, vals, E);

  // 3) aggregate + blend + relu (fused)
  aggregate<<<(N + 3) / 4, 256, 0, stream>>>(support, row_ptr, deg, cols, vals, init_in, out, N);
}

// Round 3
// 295.882 us; speedup vs baseline: 9.3952x; 1.3635x over previous
//
#include <hip/hip_runtime.h>

#define ALPHA 0.5f

typedef short short8v __attribute__((ext_vector_type(8)));
typedef float f32x4 __attribute__((ext_vector_type(4)));

__device__ __forceinline__ unsigned short f2bf(float f) {
  union { float f; unsigned u; } v; v.f = f;
  unsigned r = v.u + 0x7FFFu + ((v.u >> 16) & 1u);   // RNE
  return (unsigned short)(r >> 16);
}
__device__ __forceinline__ float bf2f(unsigned short u) {
  union { unsigned u; float f; } v; v.u = ((unsigned)u) << 16;
  return v.f;
}

// ---------------- Wt[n][k] = bf16(W[k][n]) ----------------
__global__ void transpose_w(const float* __restrict__ W, unsigned short* __restrict__ Wt) {
  __shared__ float tile[16][17];
  int kb = blockIdx.x * 16, nb = blockIdx.y * 16;
  tile[threadIdx.y][threadIdx.x] = W[(kb + threadIdx.y) * 256 + nb + threadIdx.x];
  __syncthreads();
  Wt[(nb + threadIdx.y) * 256 + kb + threadIdx.x] = f2bf(tile[threadIdx.x][threadIdx.y]);
}

// ---------------- GEMM: support(bf16) = input @ W via MFMA ----------------
// 128x128 tile, 256 threads (4 waves), each wave 64x64 = 4x4 frags of 16x16x32.
// LDS per buffer: A subtiles 0..7 (1KB each, fragment-order), B subtiles 0..7. 2 buffers.
__global__ __launch_bounds__(256) void gemm_mfma(
    const float* __restrict__ A, const unsigned short* __restrict__ Wt,
    unsigned short* __restrict__ C, int M) {
  __shared__ char smem[2][16384];
  const int tid = threadIdx.x;
  const int lane = tid & 63;
  const int w = tid >> 6;
  const int wm = w >> 1, wn = w & 1;
  const int row0 = blockIdx.x * 128, col0 = blockIdx.y * 128;

  f32x4 acc[4][4];
  #pragma unroll
  for (int m = 0; m < 4; ++m)
    #pragma unroll
    for (int n = 0; n < 4; ++n) acc[m][n] = (f32x4){0.f, 0.f, 0.f, 0.f};

  // A staging: thread t stages row aR, 16 k's starting at aKs (fp32 -> bf16 -> LDS frag-order)
  const int aR = tid >> 1;
  const int aKs = (tid & 1) * 16;
  const int aRow = (row0 + aR < M) ? (row0 + aR) : (M - 1);  // clamp (stores guarded)
  const float* aP = A + (size_t)aRow * 256 + aKs;
  const int aWrOff = (aR >> 4) * 1024 + (aKs >> 3) * 256 + (aR & 15) * 16;  // bytes

  int cur = 0;
  // prologue: stage K-tile 0 into buf 0
  {
    float4 av[4];
    #pragma unroll
    for (int j = 0; j < 4; ++j) av[j] = *reinterpret_cast<const float4*>(aP + j * 4);
    #pragma unroll
    for (int i = 0; i < 2; ++i) {
      int s = w * 2 + i;
      const unsigned short* g = Wt + (size_t)(col0 + s * 16 + (lane & 15)) * 256 + (lane >> 4) * 8;
      __builtin_amdgcn_global_load_lds(
          (const __attribute__((address_space(1))) void*)g,
          (__attribute__((address_space(3))) void*)(&smem[0][8192 + s * 1024]),
          16, 0, 0);
    }
    unsigned short ab[16];
    #pragma unroll
    for (int j = 0; j < 4; ++j) {
      ab[j * 4 + 0] = f2bf(av[j].x); ab[j * 4 + 1] = f2bf(av[j].y);
      ab[j * 4 + 2] = f2bf(av[j].z); ab[j * 4 + 3] = f2bf(av[j].w);
    }
    *reinterpret_cast<short8v*>(&smem[0][aWrOff])       = *reinterpret_cast<short8v*>(&ab[0]);
    *reinterpret_cast<short8v*>(&smem[0][aWrOff + 256]) = *reinterpret_cast<short8v*>(&ab[8]);
    __syncthreads();
  }

  #pragma unroll
  for (int t = 0; t < 8; ++t) {
    // issue prefetch of K-tile t+1 into buf cur^1
    float4 av[4];
    const bool pf = (t < 7);
    if (pf) {
      const int k0 = (t + 1) * 32;
      #pragma unroll
      for (int j = 0; j < 4; ++j) av[j] = *reinterpret_cast<const float4*>(aP + k0 + j * 4);
      #pragma unroll
      for (int i = 0; i < 2; ++i) {
        int s = w * 2 + i;
        const unsigned short* g = Wt + (size_t)(col0 + s * 16 + (lane & 15)) * 256 + k0 + (lane >> 4) * 8;
        __builtin_amdgcn_global_load_lds(
            (const __attribute__((address_space(1))) void*)g,
            (__attribute__((address_space(3))) void*)(&smem[cur ^ 1][8192 + s * 1024]),
            16, 0, 0);
      }
    }
    // compute current tile: conflict-free ds_read_b128 at base + lane*16
    short8v af[4], bf[4];
    #pragma unroll
    for (int m = 0; m < 4; ++m)
      af[m] = *reinterpret_cast<const short8v*>(&smem[cur][(wm * 4 + m) * 1024 + lane * 16]);
    #pragma unroll
    for (int n = 0; n < 4; ++n)
      bf[n] = *reinterpret_cast<const short8v*>(&smem[cur][8192 + (wn * 4 + n) * 1024 + lane * 16]);
    #pragma unroll
    for (int m = 0; m < 4; ++m)
      #pragma unroll
      for (int n = 0; n < 4; ++n)
        acc[m][n] = __builtin_amdgcn_mfma_f32_16x16x32_bf16(af[m], bf[n], acc[m][n], 0, 0, 0);
    // finish A prefetch: cvt + frag-order LDS write
    if (pf) {
      unsigned short ab[16];
      #pragma unroll
      for (int j = 0; j < 4; ++j) {
        ab[j * 4 + 0] = f2bf(av[j].x); ab[j * 4 + 1] = f2bf(av[j].y);
        ab[j * 4 + 2] = f2bf(av[j].z); ab[j * 4 + 3] = f2bf(av[j].w);
      }
      *reinterpret_cast<short8v*>(&smem[cur ^ 1][aWrOff])       = *reinterpret_cast<short8v*>(&ab[0]);
      *reinterpret_cast<short8v*>(&smem[cur ^ 1][aWrOff + 256]) = *reinterpret_cast<short8v*>(&ab[8]);
    }
    __syncthreads();
    cur ^= 1;
  }

  // epilogue: C/D layout col=lane&15, row=(lane>>4)*4+reg (m89-verified)
  #pragma unroll
  for (int m = 0; m < 4; ++m) {
    #pragma unroll
    for (int n = 0; n < 4; ++n) {
      const int col = col0 + wn * 64 + n * 16 + (lane & 15);
      #pragma unroll
      for (int r = 0; r < 4; ++r) {
        const int row = row0 + wm * 64 + m * 16 + (lane >> 4) * 4 + r;
        if (row < M) C[(size_t)row * 256 + col] = f2bf(acc[m][n][r]);
      }
    }
  }
}

// ---------------- CSR build ----------------
__global__ void histogram_dst(const int* __restrict__ dst, int* __restrict__ deg, int E) {
  int i = blockIdx.x * blockDim.x + threadIdx.x;
  if (i < E) atomicAdd(&deg[dst[i]], 1);
}

// O(N) scan: each of 1024 threads owns a contiguous chunk; one LDS scan of chunk sums.
__global__ __launch_bounds__(1024) void scan_deg(const int* __restrict__ deg,
                                                 int* __restrict__ row_ptr,
                                                 int* __restrict__ cursor, int N) {
  __shared__ int sums[1024];
  const int t = threadIdx.x;
  const int C = (N + 1023) >> 10;
  int lo = t * C, hi = lo + C; if (hi > N) hi = N; if (lo > N) lo = N;
  int s = 0;
  for (int i = lo; i < hi; ++i) s += deg[i];
  sums[t] = s;
  __syncthreads();
  #pragma unroll
  for (int off = 1; off < 1024; off <<= 1) {
    int v = (t >= off) ? sums[t - off] : 0;
    __syncthreads();
    sums[t] += v;
    __syncthreads();
  }
  int run = sums[t] - s;  // exclusive prefix of this chunk
  for (int i = lo; i < hi; ++i) {
    row_ptr[i] = run; cursor[i] = run;
    run += deg[i];
  }
}

__global__ void reindex_edges(const int* __restrict__ src, const int* __restrict__ dst,
                              const float* __restrict__ w, int* __restrict__ cursor,
                              int2* __restrict__ edges, int E) {
  int i = blockIdx.x * blockDim.x + threadIdx.x;
  if (i < E) {
    int d = dst[i];
    int slot = atomicAdd(&cursor[d], 1);
    edges[slot] = make_int2(src[i], __float_as_int(w[i] * ALPHA));  // fold alpha
  }
}

// ---------------- aggregate (pull, bf16 support), fused blend+relu ----------------
__global__ __launch_bounds__(256) void aggregate(
    const unsigned short* __restrict__ support,
    const int* __restrict__ row_ptr, const int* __restrict__ deg,
    const int2* __restrict__ edges,
    const float* __restrict__ init, float* __restrict__ out, int N) {
  int node = blockIdx.x * 4 + (threadIdx.x >> 6);
  if (node >= N) return;
  int lane = threadIdx.x & 63;
  int start = row_ptr[node], cnt = deg[node];

  float4 acc = make_float4(0.f, 0.f, 0.f, 0.f);
  int e = 0;
  for (; e + 1 < cnt; e += 2) {  // 2-edge unroll for ILP
    int2 e0 = edges[start + e], e1 = edges[start + e + 1];
    ushort4 v0 = *reinterpret_cast<const ushort4*>(&support[(size_t)e0.x * 256 + lane * 4]);
    ushort4 v1 = *reinterpret_cast<const ushort4*>(&support[(size_t)e1.x * 256 + lane * 4]);
    float w0 = __int_as_float(e0.y), w1 = __int_as_float(e1.y);
    acc.x += w0 * bf2f(v0.x) + w1 * bf2f(v1.x);
    acc.y += w0 * bf2f(v0.y) + w1 * bf2f(v1.y);
    acc.z += w0 * bf2f(v0.z) + w1 * bf2f(v1.z);
    acc.w += w0 * bf2f(v0.w) + w1 * bf2f(v1.w);
  }
  if (e < cnt) {
    int2 e0 = edges[start + e];
    ushort4 v0 = *reinterpret_cast<const ushort4*>(&support[(size_t)e0.x * 256 + lane * 4]);
    float w0 = __int_as_float(e0.y);
    acc.x += w0 * bf2f(v0.x); acc.y += w0 * bf2f(v0.y);
    acc.z += w0 * bf2f(v0.z); acc.w += w0 * bf2f(v0.w);
  }
  float4 ini = *reinterpret_cast<const float4*>(&init[(size_t)node * 256 + lane * 4]);
  float4 o;
  o.x = fmaxf(acc.x + (1.f - ALPHA) * ini.x, 0.f);
  o.y = fmaxf(acc.y + (1.f - ALPHA) * ini.y, 0.f);
  o.z = fmaxf(acc.z + (1.f - ALPHA) * ini.z, 0.f);
  o.w = fmaxf(acc.w + (1.f - ALPHA) * ini.w, 0.f);
  *reinterpret_cast<float4*>(&out[(size_t)node * 256 + lane * 4]) = o;
}

extern "C" void kernel_launch(void* const* d_in, const int* in_sizes, int n_in,
                              void* d_out, int out_size, void* d_ws, size_t ws_size,
                              hipStream_t stream) {
  const float* input   = (const float*)d_in[0];  // [N,256]
  const int*   adj_src = (const int*)d_in[1];    // [E]
  const int*   adj_dst = (const int*)d_in[2];    // [E]
  const float* adj_w   = (const float*)d_in[3];  // [E]
  const float* init_in = (const float*)d_in[4];  // [N,256]
  const float* weight  = (const float*)d_in[5];  // [256,256]
  float* out = (float*)d_out;

  const int N = in_sizes[0] / 256;  // 50000
  const int E = in_sizes[1];        // 800000

  // workspace layout (~32.7 MB)
  char* ws = (char*)d_ws;
  unsigned short* support = (unsigned short*)ws; ws += (size_t)N * 256 * 2;
  unsigned short* Wt      = (unsigned short*)ws; ws += 256 * 256 * 2;
  int* deg     = (int*)ws; ws += (size_t)N * 4;
  int* row_ptr = (int*)ws; ws += (size_t)N * 4;
  int* cursor  = (int*)ws; ws += (size_t)N * 4;
  int2* edges  = (int2*)ws; ws += (size_t)E * 8;

  transpose_w<<<dim3(16, 16), dim3(16, 16), 0, stream>>>(weight, Wt);
  gemm_mfma<<<dim3((N + 127) / 128, 2), 256, 0, stream>>>(input, Wt, support, N);

  hipMemsetAsync(deg, 0, (size_t)N * 4, stream);
  histogram_dst<<<(E + 255) / 256, 256, 0, stream>>>(adj_dst, deg, E);
  scan_deg<<<1, 1024, 0, stream>>>(deg, row_ptr, cursor, N);
  reindex_edges<<<(E + 255) / 256, 256, 0, stream>>>(adj_src, adj_dst, adj_w, cursor, edges, E);

  aggregate<<<(N + 3) / 4, 256, 0, stream>>>(support, row_ptr, deg, edges, init_in, out, N);
}

// Round 4
// 192.804 us; speedup vs baseline: 14.4182x; 1.5346x over previous
//
#include <hip/hip_runtime.h>

#define ALPHA 0.5f

typedef short short8v __attribute__((ext_vector_type(8)));
typedef float f32x4 __attribute__((ext_vector_type(4)));

__device__ __forceinline__ unsigned short f2bf(float f) {
  union { float f; unsigned u; } v; v.f = f;
  unsigned r = v.u + 0x7FFFu + ((v.u >> 16) & 1u);   // RNE
  return (unsigned short)(r >> 16);
}
__device__ __forceinline__ float bf2f(unsigned short u) {
  union { unsigned u; float f; } v; v.u = ((unsigned)u) << 16;
  return v.f;
}

// ---------------- Wt[n][k] = bf16(W[k][n]) ----------------
__global__ void transpose_w(const float* __restrict__ W, unsigned short* __restrict__ Wt) {
  __shared__ float tile[16][17];
  int kb = blockIdx.x * 16, nb = blockIdx.y * 16;
  tile[threadIdx.y][threadIdx.x] = W[(kb + threadIdx.y) * 256 + nb + threadIdx.x];
  __syncthreads();
  Wt[(nb + threadIdx.y) * 256 + kb + threadIdx.x] = f2bf(tile[threadIdx.x][threadIdx.y]);
}

// ---------------- GEMM: support(bf16) = input @ W via MFMA ----------------
__global__ __launch_bounds__(256) void gemm_mfma(
    const float* __restrict__ A, const unsigned short* __restrict__ Wt,
    unsigned short* __restrict__ C, int M) {
  __shared__ char smem[2][16384];
  const int tid = threadIdx.x;
  const int lane = tid & 63;
  const int w = tid >> 6;
  const int wm = w >> 1, wn = w & 1;
  const int row0 = blockIdx.x * 128, col0 = blockIdx.y * 128;

  f32x4 acc[4][4];
  #pragma unroll
  for (int m = 0; m < 4; ++m)
    #pragma unroll
    for (int n = 0; n < 4; ++n) acc[m][n] = (f32x4){0.f, 0.f, 0.f, 0.f};

  const int aR = tid >> 1;
  const int aKs = (tid & 1) * 16;
  const int aRow = (row0 + aR < M) ? (row0 + aR) : (M - 1);
  const float* aP = A + (size_t)aRow * 256 + aKs;
  const int aWrOff = (aR >> 4) * 1024 + (aKs >> 3) * 256 + (aR & 15) * 16;

  int cur = 0;
  {
    float4 av[4];
    #pragma unroll
    for (int j = 0; j < 4; ++j) av[j] = *reinterpret_cast<const float4*>(aP + j * 4);
    #pragma unroll
    for (int i = 0; i < 2; ++i) {
      int s = w * 2 + i;
      const unsigned short* g = Wt + (size_t)(col0 + s * 16 + (lane & 15)) * 256 + (lane >> 4) * 8;
      __builtin_amdgcn_global_load_lds(
          (const __attribute__((address_space(1))) void*)g,
          (__attribute__((address_space(3))) void*)(&smem[0][8192 + s * 1024]),
          16, 0, 0);
    }
    unsigned short ab[16];
    #pragma unroll
    for (int j = 0; j < 4; ++j) {
      ab[j * 4 + 0] = f2bf(av[j].x); ab[j * 4 + 1] = f2bf(av[j].y);
      ab[j * 4 + 2] = f2bf(av[j].z); ab[j * 4 + 3] = f2bf(av[j].w);
    }
    *reinterpret_cast<short8v*>(&smem[0][aWrOff])       = *reinterpret_cast<short8v*>(&ab[0]);
    *reinterpret_cast<short8v*>(&smem[0][aWrOff + 256]) = *reinterpret_cast<short8v*>(&ab[8]);
    __syncthreads();
  }

  #pragma unroll
  for (int t = 0; t < 8; ++t) {
    float4 av[4];
    const bool pf = (t < 7);
    if (pf) {
      const int k0 = (t + 1) * 32;
      #pragma unroll
      for (int j = 0; j < 4; ++j) av[j] = *reinterpret_cast<const float4*>(aP + k0 + j * 4);
      #pragma unroll
      for (int i = 0; i < 2; ++i) {
        int s = w * 2 + i;
        const unsigned short* g = Wt + (size_t)(col0 + s * 16 + (lane & 15)) * 256 + k0 + (lane >> 4) * 8;
        __builtin_amdgcn_global_load_lds(
            (const __attribute__((address_space(1))) void*)g,
            (__attribute__((address_space(3))) void*)(&smem[cur ^ 1][8192 + s * 1024]),
            16, 0, 0);
      }
    }
    short8v af[4], bf[4];
    #pragma unroll
    for (int m = 0; m < 4; ++m)
      af[m] = *reinterpret_cast<const short8v*>(&smem[cur][(wm * 4 + m) * 1024 + lane * 16]);
    #pragma unroll
    for (int n = 0; n < 4; ++n)
      bf[n] = *reinterpret_cast<const short8v*>(&smem[cur][8192 + (wn * 4 + n) * 1024 + lane * 16]);
    #pragma unroll
    for (int m = 0; m < 4; ++m)
      #pragma unroll
      for (int n = 0; n < 4; ++n)
        acc[m][n] = __builtin_amdgcn_mfma_f32_16x16x32_bf16(af[m], bf[n], acc[m][n], 0, 0, 0);
    if (pf) {
      unsigned short ab[16];
      #pragma unroll
      for (int j = 0; j < 4; ++j) {
        ab[j * 4 + 0] = f2bf(av[j].x); ab[j * 4 + 1] = f2bf(av[j].y);
        ab[j * 4 + 2] = f2bf(av[j].z); ab[j * 4 + 3] = f2bf(av[j].w);
      }
      *reinterpret_cast<short8v*>(&smem[cur ^ 1][aWrOff])       = *reinterpret_cast<short8v*>(&ab[0]);
      *reinterpret_cast<short8v*>(&smem[cur ^ 1][aWrOff + 256]) = *reinterpret_cast<short8v*>(&ab[8]);
    }
    __syncthreads();
    cur ^= 1;
  }

  #pragma unroll
  for (int m = 0; m < 4; ++m) {
    #pragma unroll
    for (int n = 0; n < 4; ++n) {
      const int col = col0 + wn * 64 + n * 16 + (lane & 15);
      #pragma unroll
      for (int r = 0; r < 4; ++r) {
        const int row = row0 + wm * 64 + m * 16 + (lane >> 4) * 4 + r;
        if (row < M) C[(size_t)row * 256 + col] = f2bf(acc[m][n][r]);
      }
    }
  }
}

// ---------------- CSR build ----------------
__global__ void histogram_dst(const int* __restrict__ dst, int* __restrict__ deg, int E) {
  int i = blockIdx.x * blockDim.x + threadIdx.x;
  if (i < E) atomicAdd(&deg[dst[i]], 1);
}

// Pass 1: per-block (1024 elems) exclusive scan + block totals. 256 thr, 4 elems/thr.
__global__ __launch_bounds__(256) void scan_pass1(const int* __restrict__ deg,
                                                  int* __restrict__ excl,
                                                  int* __restrict__ partial, int N) {
  const int tid = threadIdx.x;
  const int base = blockIdx.x * 1024 + tid * 4;
  int4 v = make_int4(0, 0, 0, 0);
  if (base + 3 < N) v = *reinterpret_cast<const int4*>(&deg[base]);
  else {
    if (base + 0 < N) v.x = deg[base + 0];
    if (base + 1 < N) v.y = deg[base + 1];
    if (base + 2 < N) v.z = deg[base + 2];
  }
  const int s = v.x + v.y + v.z + v.w;
  const int lane = tid & 63, wid = tid >> 6;
  int ps = s;
  #pragma unroll
  for (int off = 1; off < 64; off <<= 1) {
    int t = __shfl_up(ps, off, 64);
    if (lane >= off) ps += t;
  }
  __shared__ int wsum[4];
  if (lane == 63) wsum[wid] = ps;
  __syncthreads();
  int woff = 0;
  #pragma unroll
  for (int w2 = 0; w2 < 4; ++w2) woff += (w2 < wid) ? wsum[w2] : 0;
  const int texcl = woff + ps - s;
  int4 e = make_int4(texcl, texcl + v.x, texcl + v.x + v.y, texcl + v.x + v.y + v.z);
  if (base + 3 < N) *reinterpret_cast<int4*>(&excl[base]) = e;
  else {
    if (base + 0 < N) excl[base + 0] = e.x;
    if (base + 1 < N) excl[base + 1] = e.y;
    if (base + 2 < N) excl[base + 2] = e.z;
  }
  if (tid == 255) partial[blockIdx.x] = woff + ps;  // block total
}

// Pass 2: each block wave-reduces partial[0..blockIdx) (NB<=64) and applies offset.
__global__ __launch_bounds__(256) void scan_pass2(const int* __restrict__ excl,
                                                  const int* __restrict__ partial,
                                                  int* __restrict__ row_ptr,
                                                  int* __restrict__ cursor, int N, int NB) {
  __shared__ int s_off;
  const int tid = threadIdx.x;
  if (tid < 64) {
    int v = (tid < NB && tid < (int)blockIdx.x) ? partial[tid] : 0;
    #pragma unroll
    for (int off = 1; off < 64; off <<= 1) v += __shfl_xor(v, off, 64);
    if (tid == 0) s_off = v;
  }
  __syncthreads();
  const int off = s_off;
  const int base = blockIdx.x * 1024 + tid * 4;
  if (base + 3 < N) {
    int4 v = *reinterpret_cast<const int4*>(&excl[base]);
    v.x += off; v.y += off; v.z += off; v.w += off;
    *reinterpret_cast<int4*>(&row_ptr[base]) = v;
    *reinterpret_cast<int4*>(&cursor[base]) = v;
  } else {
    for (int j = 0; j < 4; ++j)
      if (base + j < N) { int v = excl[base + j] + off; row_ptr[base + j] = v; cursor[base + j] = v; }
  }
}

__global__ void reindex_edges(const int* __restrict__ src, const int* __restrict__ dst,
                              const float* __restrict__ w, int* __restrict__ cursor,
                              int2* __restrict__ edges, int E) {
  int i = blockIdx.x * blockDim.x + threadIdx.x;
  if (i < E) {
    int d = dst[i];
    int slot = atomicAdd(&cursor[d], 1);
    edges[slot] = make_int2(src[i], __float_as_int(w[i] * ALPHA));
  }
}

// ---------------- aggregate (pull, bf16 support), fused blend+relu ----------------
__global__ __launch_bounds__(256) void aggregate(
    const unsigned short* __restrict__ support,
    const int* __restrict__ row_ptr, const int* __restrict__ deg,
    const int2* __restrict__ edges,
    const float* __restrict__ init, float* __restrict__ out, int N) {
  int node = blockIdx.x * 4 + (threadIdx.x >> 6);
  if (node >= N) return;
  int lane = threadIdx.x & 63;
  int start = row_ptr[node], cnt = deg[node];

  float4 acc = make_float4(0.f, 0.f, 0.f, 0.f);
  int e = 0;
  for (; e + 3 < cnt; e += 4) {  // 4-edge unroll: more outstanding gathers
    int2 e0 = edges[start + e + 0], e1 = edges[start + e + 1];
    int2 e2 = edges[start + e + 2], e3 = edges[start + e + 3];
    ushort4 v0 = *reinterpret_cast<const ushort4*>(&support[(size_t)e0.x * 256 + lane * 4]);
    ushort4 v1 = *reinterpret_cast<const ushort4*>(&support[(size_t)e1.x * 256 + lane * 4]);
    ushort4 v2 = *reinterpret_cast<const ushort4*>(&support[(size_t)e2.x * 256 + lane * 4]);
    ushort4 v3 = *reinterpret_cast<const ushort4*>(&support[(size_t)e3.x * 256 + lane * 4]);
    float w0 = __int_as_float(e0.y), w1 = __int_as_float(e1.y);
    float w2 = __int_as_float(e2.y), w3 = __int_as_float(e3.y);
    acc.x += w0 * bf2f(v0.x) + w1 * bf2f(v1.x) + w2 * bf2f(v2.x) + w3 * bf2f(v3.x);
    acc.y += w0 * bf2f(v0.y) + w1 * bf2f(v1.y) + w2 * bf2f(v2.y) + w3 * bf2f(v3.y);
    acc.z += w0 * bf2f(v0.z) + w1 * bf2f(v1.z) + w2 * bf2f(v2.z) + w3 * bf2f(v3.z);
    acc.w += w0 * bf2f(v0.w) + w1 * bf2f(v1.w) + w2 * bf2f(v2.w) + w3 * bf2f(v3.w);
  }
  for (; e < cnt; ++e) {
    int2 e0 = edges[start + e];
    ushort4 v0 = *reinterpret_cast<const ushort4*>(&support[(size_t)e0.x * 256 + lane * 4]);
    float w0 = __int_as_float(e0.y);
    acc.x += w0 * bf2f(v0.x); acc.y += w0 * bf2f(v0.y);
    acc.z += w0 * bf2f(v0.z); acc.w += w0 * bf2f(v0.w);
  }
  float4 ini = *reinterpret_cast<const float4*>(&init[(size_t)node * 256 + lane * 4]);
  float4 o;
  o.x = fmaxf(acc.x + (1.f - ALPHA) * ini.x, 0.f);
  o.y = fmaxf(acc.y + (1.f - ALPHA) * ini.y, 0.f);
  o.z = fmaxf(acc.z + (1.f - ALPHA) * ini.z, 0.f);
  o.w = fmaxf(acc.w + (1.f - ALPHA) * ini.w, 0.f);
  *reinterpret_cast<float4*>(&out[(size_t)node * 256 + lane * 4]) = o;
}

extern "C" void kernel_launch(void* const* d_in, const int* in_sizes, int n_in,
                              void* d_out, int out_size, void* d_ws, size_t ws_size,
                              hipStream_t stream) {
  const float* input   = (const float*)d_in[0];
  const int*   adj_src = (const int*)d_in[1];
  const int*   adj_dst = (const int*)d_in[2];
  const float* adj_w   = (const float*)d_in[3];
  const float* init_in = (const float*)d_in[4];
  const float* weight  = (const float*)d_in[5];
  float* out = (float*)d_out;

  const int N = in_sizes[0] / 256;  // 50000
  const int E = in_sizes[1];        // 800000

  char* ws = (char*)d_ws;
  unsigned short* support = (unsigned short*)ws; ws += (size_t)N * 256 * 2;
  unsigned short* Wt      = (unsigned short*)ws; ws += 256 * 256 * 2;
  int* deg     = (int*)ws; ws += (size_t)N * 4;
  int* row_ptr = (int*)ws; ws += (size_t)N * 4;
  int* cursor  = (int*)ws; ws += (size_t)N * 4;
  int* excl    = (int*)ws; ws += (size_t)N * 4;
  int* partial = (int*)ws; ws += 256;
  int2* edges  = (int2*)ws; ws += (size_t)E * 8;

  const int NB = (N + 1023) / 1024;  // 49 (must be <= 64 for scan_pass2)

  transpose_w<<<dim3(16, 16), dim3(16, 16), 0, stream>>>(weight, Wt);
  gemm_mfma<<<dim3((N + 127) / 128, 2), 256, 0, stream>>>(input, Wt, support, N);

  hipMemsetAsync(deg, 0, (size_t)N * 4, stream);
  histogram_dst<<<(E + 255) / 256, 256, 0, stream>>>(adj_dst, deg, E);
  scan_pass1<<<NB, 256, 0, stream>>>(deg, excl, partial, N);
  scan_pass2<<<NB, 256, 0, stream>>>(excl, partial, row_ptr, cursor, N, NB);
  reindex_edges<<<(E + 255) / 256, 256, 0, stream>>>(adj_src, adj_dst, adj_w, cursor, edges, E);

  aggregate<<<(N + 3) / 4, 256, 0, stream>>>(support, row_ptr, deg, edges, init_in, out, N);
}

// Round 5
// 191.770 us; speedup vs baseline: 14.4959x; 1.0054x over previous
//
#include <hip/hip_runtime.h>
#include <hip/hip_fp16.h>

#define ALPHA 0.5f

typedef short short8v __attribute__((ext_vector_type(8)));
typedef float f32x4 __attribute__((ext_vector_type(4)));

__device__ __forceinline__ unsigned short f2bf(float f) {
  union { float f; unsigned u; } v; v.f = f;
  unsigned r = v.u + 0x7FFFu + ((v.u >> 16) & 1u);   // RNE
  return (unsigned short)(r >> 16);
}
__device__ __forceinline__ float bf2f(unsigned short u) {
  union { unsigned u; float f; } v; v.u = ((unsigned)u) << 16;
  return v.f;
}

// ---------------- Wt[n][k] = bf16(W[k][n]) ----------------
__global__ void transpose_w(const float* __restrict__ W, unsigned short* __restrict__ Wt) {
  __shared__ float tile[16][17];
  int kb = blockIdx.x * 16, nb = blockIdx.y * 16;
  tile[threadIdx.y][threadIdx.x] = W[(kb + threadIdx.y) * 256 + nb + threadIdx.x];
  __syncthreads();
  Wt[(nb + threadIdx.y) * 256 + kb + threadIdx.x] = f2bf(tile[threadIdx.x][threadIdx.y]);
}

// ---------------- GEMM: support(bf16) = input @ W via MFMA ----------------
// 128x256 tile (full N), 256 threads (4 waves), each wave 64x128 = 4x8 frags of 16x16x32.
// A read exactly once. LDS per buffer: A 8x1KB + B 16x1KB = 24KB; double-buffered.
__global__ __launch_bounds__(256) void gemm_mfma(
    const float* __restrict__ A, const unsigned short* __restrict__ Wt,
    unsigned short* __restrict__ C, int M) {
  __shared__ char smem[2][24576];
  const int tid = threadIdx.x;
  const int lane = tid & 63;
  const int w = tid >> 6;
  const int wm = w >> 1, wn = w & 1;
  const int row0 = blockIdx.x * 128;

  f32x4 acc[4][8];
  #pragma unroll
  for (int m = 0; m < 4; ++m)
    #pragma unroll
    for (int n = 0; n < 8; ++n) acc[m][n] = (f32x4){0.f, 0.f, 0.f, 0.f};

  const int aR = tid >> 1;
  const int aKs = (tid & 1) * 16;
  const int aRow = (row0 + aR < M) ? (row0 + aR) : (M - 1);
  const float* aP = A + (size_t)aRow * 256 + aKs;
  const int aWrOff = (aR >> 4) * 1024 + (aKs >> 3) * 256 + (aR & 15) * 16;

  int cur = 0;
  // prologue: stage K-tile 0
  {
    float4 av[4];
    #pragma unroll
    for (int j = 0; j < 4; ++j) av[j] = *reinterpret_cast<const float4*>(aP + j * 4);
    #pragma unroll
    for (int i = 0; i < 4; ++i) {
      int s = w * 4 + i;
      const unsigned short* g = Wt + (size_t)(s * 16 + (lane & 15)) * 256 + (lane >> 4) * 8;
      __builtin_amdgcn_global_load_lds(
          (const __attribute__((address_space(1))) void*)g,
          (__attribute__((address_space(3))) void*)(&smem[0][8192 + s * 1024]),
          16, 0, 0);
    }
    unsigned short ab[16];
    #pragma unroll
    for (int j = 0; j < 4; ++j) {
      ab[j * 4 + 0] = f2bf(av[j].x); ab[j * 4 + 1] = f2bf(av[j].y);
      ab[j * 4 + 2] = f2bf(av[j].z); ab[j * 4 + 3] = f2bf(av[j].w);
    }
    *reinterpret_cast<short8v*>(&smem[0][aWrOff])       = *reinterpret_cast<short8v*>(&ab[0]);
    *reinterpret_cast<short8v*>(&smem[0][aWrOff + 256]) = *reinterpret_cast<short8v*>(&ab[8]);
    __syncthreads();
  }

  #pragma unroll
  for (int t = 0; t < 8; ++t) {
    float4 av[4];
    const bool pf = (t < 7);
    if (pf) {
      const int k0 = (t + 1) * 32;
      #pragma unroll
      for (int j = 0; j < 4; ++j) av[j] = *reinterpret_cast<const float4*>(aP + k0 + j * 4);
      #pragma unroll
      for (int i = 0; i < 4; ++i) {
        int s = w * 4 + i;
        const unsigned short* g = Wt + (size_t)(s * 16 + (lane & 15)) * 256 + k0 + (lane >> 4) * 8;
        __builtin_amdgcn_global_load_lds(
            (const __attribute__((address_space(1))) void*)g,
            (__attribute__((address_space(3))) void*)(&smem[cur ^ 1][8192 + s * 1024]),
            16, 0, 0);
      }
    }
    short8v af[4], bfv[8];
    #pragma unroll
    for (int m = 0; m < 4; ++m)
      af[m] = *reinterpret_cast<const short8v*>(&smem[cur][(wm * 4 + m) * 1024 + lane * 16]);
    #pragma unroll
    for (int n = 0; n < 8; ++n)
      bfv[n] = *reinterpret_cast<const short8v*>(&smem[cur][8192 + (wn * 8 + n) * 1024 + lane * 16]);
    #pragma unroll
    for (int m = 0; m < 4; ++m)
      #pragma unroll
      for (int n = 0; n < 8; ++n)
        acc[m][n] = __builtin_amdgcn_mfma_f32_16x16x32_bf16(af[m], bfv[n], acc[m][n], 0, 0, 0);
    if (pf) {
      unsigned short ab[16];
      #pragma unroll
      for (int j = 0; j < 4; ++j) {
        ab[j * 4 + 0] = f2bf(av[j].x); ab[j * 4 + 1] = f2bf(av[j].y);
        ab[j * 4 + 2] = f2bf(av[j].z); ab[j * 4 + 3] = f2bf(av[j].w);
      }
      *reinterpret_cast<short8v*>(&smem[cur ^ 1][aWrOff])       = *reinterpret_cast<short8v*>(&ab[0]);
      *reinterpret_cast<short8v*>(&smem[cur ^ 1][aWrOff + 256]) = *reinterpret_cast<short8v*>(&ab[8]);
    }
    __syncthreads();
    cur ^= 1;
  }

  #pragma unroll
  for (int m = 0; m < 4; ++m) {
    #pragma unroll
    for (int n = 0; n < 8; ++n) {
      const int col = wn * 128 + n * 16 + (lane & 15);
      #pragma unroll
      for (int r = 0; r < 4; ++r) {
        const int row = row0 + wm * 64 + m * 16 + (lane >> 4) * 4 + r;
        if (row < M) C[(size_t)row * 256 + col] = f2bf(acc[m][n][r]);
      }
    }
  }
}

// ---------------- CSR build ----------------
__global__ void histogram_dst(const int* __restrict__ dst, int* __restrict__ deg, int E) {
  int i = blockIdx.x * blockDim.x + threadIdx.x;
  if (i < E) atomicAdd(&deg[dst[i]], 1);
}

__global__ __launch_bounds__(256) void scan_pass1(const int* __restrict__ deg,
                                                  int* __restrict__ excl,
                                                  int* __restrict__ partial, int N) {
  const int tid = threadIdx.x;
  const int base = blockIdx.x * 1024 + tid * 4;
  int4 v = make_int4(0, 0, 0, 0);
  if (base + 3 < N) v = *reinterpret_cast<const int4*>(&deg[base]);
  else {
    if (base + 0 < N) v.x = deg[base + 0];
    if (base + 1 < N) v.y = deg[base + 1];
    if (base + 2 < N) v.z = deg[base + 2];
  }
  const int s = v.x + v.y + v.z + v.w;
  const int lane = tid & 63, wid = tid >> 6;
  int ps = s;
  #pragma unroll
  for (int off = 1; off < 64; off <<= 1) {
    int t = __shfl_up(ps, off, 64);
    if (lane >= off) ps += t;
  }
  __shared__ int wsum[4];
  if (lane == 63) wsum[wid] = ps;
  __syncthreads();
  int woff = 0;
  #pragma unroll
  for (int w2 = 0; w2 < 4; ++w2) woff += (w2 < wid) ? wsum[w2] : 0;
  const int texcl = woff + ps - s;
  int4 e = make_int4(texcl, texcl + v.x, texcl + v.x + v.y, texcl + v.x + v.y + v.z);
  if (base + 3 < N) *reinterpret_cast<int4*>(&excl[base]) = e;
  else {
    if (base + 0 < N) excl[base + 0] = e.x;
    if (base + 1 < N) excl[base + 1] = e.y;
    if (base + 2 < N) excl[base + 2] = e.z;
  }
  if (tid == 255) partial[blockIdx.x] = woff + ps;
}

__global__ __launch_bounds__(256) void scan_pass2(const int* __restrict__ excl,
                                                  const int* __restrict__ partial,
                                                  int* __restrict__ row_ptr,
                                                  int* __restrict__ cursor, int N, int NB) {
  __shared__ int s_off;
  const int tid = threadIdx.x;
  if (tid < 64) {
    int v = (tid < NB && tid < (int)blockIdx.x) ? partial[tid] : 0;
    #pragma unroll
    for (int off = 1; off < 64; off <<= 1) v += __shfl_xor(v, off, 64);
    if (tid == 0) s_off = v;
  }
  __syncthreads();
  const int off = s_off;
  const int base = blockIdx.x * 1024 + tid * 4;
  if (base + 3 < N) {
    int4 v = *reinterpret_cast<const int4*>(&excl[base]);
    v.x += off; v.y += off; v.z += off; v.w += off;
    *reinterpret_cast<int4*>(&row_ptr[base]) = v;
    *reinterpret_cast<int4*>(&cursor[base]) = v;
  } else {
    for (int j = 0; j < 4; ++j)
      if (base + j < N) { int v = excl[base + j] + off; row_ptr[base + j] = v; cursor[base + j] = v; }
  }
}

// edge word: src (17 bits) << 15 | fp16(w*alpha) >> 1 (15 bits; w*alpha in [0,0.5])
__global__ void reindex_edges(const int* __restrict__ src, const int* __restrict__ dst,
                              const float* __restrict__ w, int* __restrict__ cursor,
                              unsigned* __restrict__ edges, int E) {
  int i = blockIdx.x * blockDim.x + threadIdx.x;
  if (i < E) {
    int d = dst[i];
    int slot = atomicAdd(&cursor[d], 1);
    unsigned hb = __half_as_ushort(__float2half(w[i] * ALPHA));
    edges[slot] = ((unsigned)src[i] << 15) | (hb >> 1);
  }
}

__device__ __forceinline__ float unpack_w(unsigned p) {
  return __half2float(__ushort_as_half((unsigned short)((p & 0x7FFFu) << 1)));
}

// ---------------- aggregate (pull, bf16 support), fused blend+relu ----------------
__global__ __launch_bounds__(256) void aggregate(
    const unsigned short* __restrict__ support,
    const int* __restrict__ row_ptr, const int* __restrict__ deg,
    const unsigned* __restrict__ edges,
    const float* __restrict__ init, float* __restrict__ out, int N) {
  int node = blockIdx.x * 4 + (threadIdx.x >> 6);
  if (node >= N) return;
  int lane = threadIdx.x & 63;
  int start = row_ptr[node], cnt = deg[node];

  // hoist the streaming init load above the gather loop
  float4 ini = *reinterpret_cast<const float4*>(&init[(size_t)node * 256 + lane * 4]);

  float4 acc = make_float4(0.f, 0.f, 0.f, 0.f);
  int e = 0;
  for (; e + 7 < cnt; e += 8) {  // 8 outstanding 512B gathers per wave
    unsigned p[8];
    #pragma unroll
    for (int j = 0; j < 8; ++j) p[j] = edges[start + e + j];
    ushort4 v[8];
    #pragma unroll
    for (int j = 0; j < 8; ++j)
      v[j] = *reinterpret_cast<const ushort4*>(&support[(size_t)(p[j] >> 15) * 256 + lane * 4]);
    #pragma unroll
    for (int j = 0; j < 8; ++j) {
      float wj = unpack_w(p[j]);
      acc.x += wj * bf2f(v[j].x);
      acc.y += wj * bf2f(v[j].y);
      acc.z += wj * bf2f(v[j].z);
      acc.w += wj * bf2f(v[j].w);
    }
  }
  for (; e < cnt; ++e) {
    unsigned p = edges[start + e];
    ushort4 v = *reinterpret_cast<const ushort4*>(&support[(size_t)(p >> 15) * 256 + lane * 4]);
    float wj = unpack_w(p);
    acc.x += wj * bf2f(v.x); acc.y += wj * bf2f(v.y);
    acc.z += wj * bf2f(v.z); acc.w += wj * bf2f(v.w);
  }
  float4 o;
  o.x = fmaxf(acc.x + (1.f - ALPHA) * ini.x, 0.f);
  o.y = fmaxf(acc.y + (1.f - ALPHA) * ini.y, 0.f);
  o.z = fmaxf(acc.z + (1.f - ALPHA) * ini.z, 0.f);
  o.w = fmaxf(acc.w + (1.f - ALPHA) * ini.w, 0.f);
  *reinterpret_cast<float4*>(&out[(size_t)node * 256 + lane * 4]) = o;
}

extern "C" void kernel_launch(void* const* d_in, const int* in_sizes, int n_in,
                              void* d_out, int out_size, void* d_ws, size_t ws_size,
                              hipStream_t stream) {
  const float* input   = (const float*)d_in[0];
  const int*   adj_src = (const int*)d_in[1];
  const int*   adj_dst = (const int*)d_in[2];
  const float* adj_w   = (const float*)d_in[3];
  const float* init_in = (const float*)d_in[4];
  const float* weight  = (const float*)d_in[5];
  float* out = (float*)d_out;

  const int N = in_sizes[0] / 256;  // 50000
  const int E = in_sizes[1];        // 800000

  char* ws = (char*)d_ws;
  unsigned short* support = (unsigned short*)ws; ws += (size_t)N * 256 * 2;
  unsigned short* Wt      = (unsigned short*)ws; ws += 256 * 256 * 2;
  int* deg     = (int*)ws; ws += (size_t)N * 4;
  int* row_ptr = (int*)ws; ws += (size_t)N * 4;
  int* cursor  = (int*)ws; ws += (size_t)N * 4;
  int* excl    = (int*)ws; ws += (size_t)N * 4;
  int* partial = (int*)ws; ws += 256;
  unsigned* edges = (unsigned*)ws; ws += (size_t)E * 4;

  const int NB = (N + 1023) / 1024;  // 49 (<= 64 required by scan_pass2)

  transpose_w<<<dim3(16, 16), dim3(16, 16), 0, stream>>>(weight, Wt);
  gemm_mfma<<<dim3((N + 127) / 128), 256, 0, stream>>>(input, Wt, support, N);

  hipMemsetAsync(deg, 0, (size_t)N * 4, stream);
  histogram_dst<<<(E + 255) / 256, 256, 0, stream>>>(adj_dst, deg, E);
  scan_pass1<<<NB, 256, 0, stream>>>(deg, excl, partial, N);
  scan_pass2<<<NB, 256, 0, stream>>>(excl, partial, row_ptr, cursor, N, NB);
  reindex_edges<<<(E + 255) / 256, 256, 0, stream>>>(adj_src, adj_dst, adj_w, cursor, edges, E);

  aggregate<<<(N + 3) / 4, 256, 0, stream>>>(support, row_ptr, deg, edges, init_in, out, N);
}